// Round 1
// baseline (356.026 us; speedup 1.0000x reference)
//
#include <hip/hip_runtime.h>
#include <stdint.h>

#define L_ 4096
#define S_ 256
#define D_ 512
#define NW 64  // 64-bit words per length-4096 row

static __device__ const float LN2F = 0.69314718055994530942f;

// ---------------- init: zero accumulators ----------------
__global__ void k_init(float* __restrict__ out, float* __restrict__ ent) {
    int i = blockIdx.x * blockDim.x + threadIdx.x;
    if (i < S_) out[S_ + i] = 0.0f;   // nll accumulators
    if (i < 3)  ent[i] = 0.0f;        // entropy accumulators
}

// ---------------- per-position logits -> logp ----------------
__global__ __launch_bounds__(256)
void k_rows(const int* __restrict__ x, const float* __restrict__ embd,
            const float* __restrict__ w1, const float* __restrict__ b1,
            const float* __restrict__ w2, const float* __restrict__ b2,
            const float* __restrict__ w3, const float* __restrict__ b3,
            float* __restrict__ lp, float* __restrict__ ent) {
    const int t = blockIdx.x;
    const int tid = threadIdx.x;
    const float* e0 = embd + (size_t)x[t] * D_;
    const float* e1 = embd + (size_t)x[(t + 1 < L_) ? t + 1 : t] * D_;
    const float* e2 = embd + (size_t)x[(t + 2 < L_) ? t + 2 : t] * D_;
    double a0=0,a1=0,a2=0,a3=0,a4=0,a5=0;
    for (int d = tid; d < D_; d += 256) {
        float v0 = e0[d], v1 = e1[d], v2 = e2[d];
        float s2 = (v1 + v0) * 0.5f;          // matches (emb[t+1]+emb[t])/2 in f32
        float s3 = ((v2 + v1) + v0) / 3.0f;   // matches reference order in f32
        a0 += (double)v0 * (double)w1[2*d];
        a1 += (double)v0 * (double)w1[2*d+1];
        a2 += (double)s2 * (double)w2[2*d];
        a3 += (double)s2 * (double)w2[2*d+1];
        a4 += (double)s3 * (double)w3[2*d];
        a5 += (double)s3 * (double)w3[2*d+1];
    }
    __shared__ double red[6][256];
    red[0][tid]=a0; red[1][tid]=a1; red[2][tid]=a2;
    red[3][tid]=a3; red[4][tid]=a4; red[5][tid]=a5;
    __syncthreads();
    for (int s = 128; s > 0; s >>= 1) {
        if (tid < s)
            for (int k = 0; k < 6; k++) red[k][tid] += red[k][tid + s];
        __syncthreads();
    }
    if (tid == 0) {
        {   // head 1 (valid all t)
            double l0 = red[0][0] + (double)b1[0];
            double l1 = red[1][0] + (double)b1[1];
            double m = fmax(l0, l1);
            double sa = l0 - m, sb = l1 - m;
            double lse = log(exp(sa) + exp(sb));
            float p0l = (float)(sa - lse), p1l = (float)(sb - lse);
            lp[t] = p0l; lp[L_ + t] = p1l;
            float p0 = expf(p0l), p1 = expf(p1l);
            atomicAdd(&ent[0], -(p0*p0l + p1*p1l) / LN2F);
        }
        if (t < L_-1) {  // head 2
            double l0 = red[2][0] + (double)b2[0];
            double l1 = red[3][0] + (double)b2[1];
            double m = fmax(l0, l1);
            double sa = l0 - m, sb = l1 - m;
            double lse = log(exp(sa) + exp(sb));
            float p0l = (float)(sa - lse), p1l = (float)(sb - lse);
            lp[2*L_ + t] = p0l; lp[3*L_ + t] = p1l;
            float p0 = expf(p0l), p1 = expf(p1l);
            atomicAdd(&ent[1], -(p0*p0l + p1*p1l) / LN2F);
        }
        if (t < L_-2) {  // head 3
            double l0 = red[4][0] + (double)b3[0];
            double l1 = red[5][0] + (double)b3[1];
            double m = fmax(l0, l1);
            double sa = l0 - m, sb = l1 - m;
            double lse = log(exp(sa) + exp(sb));
            float p0l = (float)(sa - lse), p1l = (float)(sb - lse);
            lp[4*L_ + t] = p0l; lp[5*L_ + t] = p1l;
            float p0 = expf(p0l), p1 = expf(p1l);
            atomicAdd(&ent[2], -(p0*p0l + p1*p1l) / LN2F);
        }
    }
}

// ---------------- pre-conflict bools, packed via ballot; nll1 ----------------
__global__ __launch_bounds__(256)
void k_pre(const float* __restrict__ lp,
           const int* __restrict__ al1, const int* __restrict__ al2, const int* __restrict__ al3,
           const float2* __restrict__ g1, const float2* __restrict__ g2, const float2* __restrict__ g3,
           uint64_t* __restrict__ p1w, uint64_t* __restrict__ p2w, uint64_t* __restrict__ p3w,
           float* __restrict__ nll) {
    const int s = blockIdx.y;
    const int t = blockIdx.x * 256 + threadIdx.x;
    const int tid = threadIdx.x;

    float2 v1 = g1[(size_t)s * L_ + t];
    float lp0 = lp[t], lp1v = lp[L_ + t];
    bool raw1 = (lp0 + v1.x) >= (lp1v + v1.y);       // argmax ties -> idx 0
    bool m1 = raw1 && (al1[t] != 0);
    float contrib = raw1 ? -lp0 : -lp1v;             // nll1 uses pre-align argmax

    bool m2 = false, m3 = false;
    if (t < L_-1) {
        float2 v2 = g2[(size_t)s * (L_-1) + t];
        m2 = ((lp[2*L_+t] + v2.x) >= (lp[3*L_+t] + v2.y)) && (al2[t] != 0);
    }
    if (t < L_-2) {
        float2 v3 = g3[(size_t)s * (L_-2) + t];
        m3 = ((lp[4*L_+t] + v3.x) >= (lp[5*L_+t] + v3.y)) && (al3[t] != 0);
    }
    unsigned long long w1b = __ballot(m1);
    unsigned long long w2b = __ballot(m2);
    unsigned long long w3b = __ballot(m3);
    if ((tid & 63) == 0) {
        int w = t >> 6;            // word-major layout [word][sample]
        p1w[(size_t)w * S_ + s] = w1b;
        p2w[(size_t)w * S_ + s] = w2b;
        p3w[(size_t)w * S_ + s] = w3b;
    }
    __shared__ float red[256];
    red[tid] = contrib;
    __syncthreads();
    for (int k = 128; k > 0; k >>= 1) {
        if (tid < k) red[tid] += red[tid + k];
        __syncthreads();
    }
    if (tid == 0) atomicAdd(&nll[s], red[0]);
}

// ---------------- word-parallel conflict scans ----------------
// pass1: out[t] = c[t] & ~out[t-1]  (alternating within runs)
__device__ __forceinline__ uint64_t pass1_word(uint64_t w, unsigned& carry) {
    uint64_t wp = w & ~(uint64_t)carry;       // forced zero at bit0 if carry out was 1
    uint64_t o = wp & ~(wp << 1);             // run starts (seeds)
    uint64_t h = wp & (wp << 1);              // can hop t-2 -> t
    o |= (o << 2)  & h; h &= (h << 2);
    o |= (o << 4)  & h; h &= (h << 4);
    o |= (o << 8)  & h; h &= (h << 8);
    o |= (o << 16) & h; h &= (h << 16);
    o |= (o << 32) & h;
    carry = (unsigned)(o >> 63);
    return o;
}
// pass2: out[t] = a[t] & ~out[t-2]  (two interleaved chains)
__device__ __forceinline__ uint64_t pass2_word(uint64_t a, unsigned& qe, unsigned& qo) {
    uint64_t ap = a & ~(uint64_t)qe & ~(((uint64_t)qo) << 1);
    uint64_t o = ap & ~(ap << 2);
    uint64_t h = ap & (ap << 2);
    o |= (o << 4)  & h; h &= (h << 4);
    o |= (o << 8)  & h; h &= (h << 8);
    o |= (o << 16) & h; h &= (h << 16);
    o |= (o << 32) & h;
    qe = (unsigned)((o >> 62) & 1);
    qo = (unsigned)(o >> 63);
    return o;
}

__global__ void k_scan(const uint64_t* __restrict__ p1w, const uint64_t* __restrict__ p2w,
                       const uint64_t* __restrict__ p3w,
                       uint64_t* __restrict__ o1w, uint64_t* __restrict__ o2w,
                       uint64_t* __restrict__ o3w) {
    const int s = blockIdx.x * 64 + threadIdx.x;  // one lane per sample
    unsigned c1 = 0, qe = 0, qo = 0, c2 = 0;
    uint64_t b3m1 = 0, b2m1 = 0;
    uint64_t b3cur = pass2_word(pass1_word(p3w[s], c1), qe, qo);
    for (int j = 0; j < NW; j++) {
        uint64_t b3nx = 0;
        if (j < NW - 1) b3nx = pass2_word(pass1_word(p3w[(size_t)(j+1)*S_ + s], c1), qe, qo);
        uint64_t sh1 = (b3cur << 1) | (b3m1 >> 63);    // b3[j-1]
        uint64_t sh2 = (b3cur << 2) | (b3m1 >> 62);    // b3[j-2]
        uint64_t shm = (b3cur >> 1) | (b3nx << 63);    // b3[j+1]
        uint64_t hit2 = b3cur | sh1 | sh2 | shm;
        uint64_t B2 = pass1_word(p2w[(size_t)j*S_ + s] & ~hit2, c2);
        uint64_t hit1 = b3cur | sh1 | sh2 | B2 | ((B2 << 1) | (b2m1 >> 63));
        uint64_t B1 = p1w[(size_t)j*S_ + s] & ~hit1;
        o3w[(size_t)j*S_ + s] = b3cur;
        o2w[(size_t)j*S_ + s] = B2;
        o1w[(size_t)j*S_ + s] = B1;
        b2m1 = B2; b3m1 = b3cur; b3cur = b3nx;
    }
}

// ---------------- unpack to floats + nll2/nll3 ----------------
__global__ __launch_bounds__(256)
void k_unpack(const uint64_t* __restrict__ o1w, const uint64_t* __restrict__ o2w,
              const uint64_t* __restrict__ o3w, const float* __restrict__ lp,
              float* __restrict__ out) {
    const int s = blockIdx.y;
    const int t = blockIdx.x * 256 + threadIdx.x;
    const int tid = threadIdx.x;
    const int w = t >> 6, b = t & 63;
    float* b1o = out + 2*S_;
    float* b2o = b1o + (size_t)S_ * L_;
    float* b3o = b2o + (size_t)S_ * (L_-1);
    float contrib = 0.0f;
    b1o[(size_t)s*L_ + t] = (float)((o1w[(size_t)w*S_ + s] >> b) & 1);
    if (t < L_-1) {
        unsigned bit = (unsigned)((o2w[(size_t)w*S_ + s] >> b) & 1);
        b2o[(size_t)s*(L_-1) + t] = (float)bit;
        contrib += bit ? -lp[2*L_+t] : -lp[3*L_+t];
    }
    if (t < L_-2) {
        unsigned bit = (unsigned)((o3w[(size_t)w*S_ + s] >> b) & 1);
        b3o[(size_t)s*(L_-2) + t] = (float)bit;
        contrib += bit ? -lp[4*L_+t] : -lp[5*L_+t];
    }
    __shared__ float red[256];
    red[tid] = contrib;
    __syncthreads();
    for (int k = 128; k > 0; k >>= 1) {
        if (tid < k) red[tid] += red[tid + k];
        __syncthreads();
    }
    if (tid == 0) atomicAdd(&out[S_ + s], red[0]);
}

// ---------------- broadcast nent ----------------
__global__ void k_nent(const float* __restrict__ ent, float* __restrict__ out) {
    float v = (ent[0] / (float)L_ + ent[1] / (float)(L_-1) + ent[2] / (float)(L_-2)) / 3.0f;
    out[threadIdx.x] = v;
}

extern "C" void kernel_launch(void* const* d_in, const int* in_sizes, int n_in,
                              void* d_out, int out_size, void* d_ws, size_t ws_size,
                              hipStream_t stream) {
    const int*   x    = (const int*)d_in[0];
    // d_in[1] = sample_num (=256), unused
    const int*   al1  = (const int*)d_in[2];
    const int*   al2  = (const int*)d_in[3];
    const int*   al3  = (const int*)d_in[4];
    const float* embd = (const float*)d_in[5];
    const float* w1   = (const float*)d_in[6];
    const float* b1   = (const float*)d_in[7];
    const float* w2   = (const float*)d_in[8];
    const float* b2   = (const float*)d_in[9];
    const float* w3   = (const float*)d_in[10];
    const float* b3   = (const float*)d_in[11];
    const float2* g1  = (const float2*)d_in[12];
    const float2* g2  = (const float2*)d_in[13];
    const float2* g3  = (const float2*)d_in[14];
    float* out = (float*)d_out;

    // ws layout: lp[6][4096] floats | ent[3] floats | 6 x u64[64][256]
    float* lp  = (float*)d_ws;
    float* ent = lp + 6 * L_;
    uint8_t* wsb = (uint8_t*)d_ws;
    uint64_t* p1w = (uint64_t*)(wsb + 98432);
    uint64_t* p2w = p1w + (size_t)NW * S_;
    uint64_t* p3w = p2w + (size_t)NW * S_;
    uint64_t* o1w = p3w + (size_t)NW * S_;
    uint64_t* o2w = o1w + (size_t)NW * S_;
    uint64_t* o3w = o2w + (size_t)NW * S_;

    hipLaunchKernelGGL(k_init, dim3(1), dim3(512), 0, stream, out, ent);
    hipLaunchKernelGGL(k_rows, dim3(L_), dim3(256), 0, stream,
                       x, embd, w1, b1, w2, b2, w3, b3, lp, ent);
    hipLaunchKernelGGL(k_pre, dim3(16, S_), dim3(256), 0, stream,
                       lp, al1, al2, al3, g1, g2, g3, p1w, p2w, p3w, out + S_);
    hipLaunchKernelGGL(k_scan, dim3(4), dim3(64), 0, stream,
                       p1w, p2w, p3w, o1w, o2w, o3w);
    hipLaunchKernelGGL(k_unpack, dim3(16, S_), dim3(256), 0, stream,
                       o1w, o2w, o3w, lp, out);
    hipLaunchKernelGGL(k_nent, dim3(1), dim3(256), 0, stream, ent, out);
}

// Round 2
// 272.080 us; speedup vs baseline: 1.3085x; 1.3085x over previous
//
#include <hip/hip_runtime.h>
#include <stdint.h>

#define L_ 4096
#define S_ 256
#define D_ 512
#define NW 64  // 64-bit words per length-4096 row

static __device__ const float LN2F = 0.69314718055994530942f;

// ---------------- init: zero nll accumulators ----------------
__global__ void k_init(float* __restrict__ out) {
    int i = blockIdx.x * blockDim.x + threadIdx.x;
    if (i < S_) out[S_ + i] = 0.0f;   // nll accumulators
}

// ---------------- per-position logits -> logp (one wave per position) ----------------
__global__ __launch_bounds__(256)
void k_rows(const int* __restrict__ x, const float* __restrict__ embd,
            const float* __restrict__ w1, const float* __restrict__ b1,
            const float* __restrict__ w2, const float* __restrict__ b2,
            const float* __restrict__ w3, const float* __restrict__ b3,
            float* __restrict__ lp, float* __restrict__ entbuf) {
    const int wid  = threadIdx.x >> 6;
    const int lane = threadIdx.x & 63;
    const int t = blockIdx.x * 4 + wid;           // grid 1024 -> t in [0,4096)
    const int t1 = (t + 1 < L_) ? t + 1 : t;
    const int t2 = (t + 2 < L_) ? t + 2 : t;
    const int d0 = lane * 8;

    const float4* e0p = (const float4*)(embd + (size_t)x[t]  * D_ + d0);
    const float4* e1p = (const float4*)(embd + (size_t)x[t1] * D_ + d0);
    const float4* e2p = (const float4*)(embd + (size_t)x[t2] * D_ + d0);
    float4 e0a = e0p[0], e0b = e0p[1];
    float4 e1a = e1p[0], e1b = e1p[1];
    float4 e2a = e2p[0], e2b = e2p[1];
    // w layout (D,2) row-major: 16 floats per lane per head
    const float4* w1p = (const float4*)(w1 + 2 * d0);
    const float4* w2p = (const float4*)(w2 + 2 * d0);
    const float4* w3p = (const float4*)(w3 + 2 * d0);

    float v0[8] = {e0a.x,e0a.y,e0a.z,e0a.w,e0b.x,e0b.y,e0b.z,e0b.w};
    float v1[8] = {e1a.x,e1a.y,e1a.z,e1a.w,e1b.x,e1b.y,e1b.z,e1b.w};
    float v2[8] = {e2a.x,e2a.y,e2a.z,e2a.w,e2b.x,e2b.y,e2b.z,e2b.w};
    float wv1[16], wv2[16], wv3[16];
    for (int q = 0; q < 4; q++) {
        float4 a = w1p[q]; wv1[4*q]=a.x; wv1[4*q+1]=a.y; wv1[4*q+2]=a.z; wv1[4*q+3]=a.w;
        float4 b = w2p[q]; wv2[4*q]=b.x; wv2[4*q+1]=b.y; wv2[4*q+2]=b.z; wv2[4*q+3]=b.w;
        float4 c = w3p[q]; wv3[4*q]=c.x; wv3[4*q+1]=c.y; wv3[4*q+2]=c.z; wv3[4*q+3]=c.w;
    }
    double a0=0,a1=0,a2=0,a3=0,a4=0,a5=0;
    #pragma unroll
    for (int j = 0; j < 8; j++) {
        float s2 = (v1[j] + v0[j]) * 0.5f;        // reference order in f32
        float s3 = ((v2[j] + v1[j]) + v0[j]) / 3.0f;
        a0 += (double)v0[j] * (double)wv1[2*j];
        a1 += (double)v0[j] * (double)wv1[2*j+1];
        a2 += (double)s2    * (double)wv2[2*j];
        a3 += (double)s2    * (double)wv2[2*j+1];
        a4 += (double)s3    * (double)wv3[2*j];
        a5 += (double)s3    * (double)wv3[2*j+1];
    }
    #pragma unroll
    for (int o = 32; o > 0; o >>= 1) {
        a0 += __shfl_xor(a0, o, 64);
        a1 += __shfl_xor(a1, o, 64);
        a2 += __shfl_xor(a2, o, 64);
        a3 += __shfl_xor(a3, o, 64);
        a4 += __shfl_xor(a4, o, 64);
        a5 += __shfl_xor(a5, o, 64);
    }
    if (lane == 0) {
        float e1v, e2v = 0.0f, e3v = 0.0f;
        {   // head 1
            double l0 = a0 + (double)b1[0], l1 = a1 + (double)b1[1];
            double m = fmax(l0, l1);
            double sa = l0 - m, sb = l1 - m;
            double lse = log(exp(sa) + exp(sb));
            float p0l = (float)(sa - lse), p1l = (float)(sb - lse);
            lp[t] = p0l; lp[L_ + t] = p1l;
            float p0 = expf(p0l), p1 = expf(p1l);
            e1v = -(p0*p0l + p1*p1l) / LN2F;
        }
        if (t < L_-1) {  // head 2
            double l0 = a2 + (double)b2[0], l1 = a3 + (double)b2[1];
            double m = fmax(l0, l1);
            double sa = l0 - m, sb = l1 - m;
            double lse = log(exp(sa) + exp(sb));
            float p0l = (float)(sa - lse), p1l = (float)(sb - lse);
            lp[2*L_ + t] = p0l; lp[3*L_ + t] = p1l;
            float p0 = expf(p0l), p1 = expf(p1l);
            e2v = -(p0*p0l + p1*p1l) / LN2F;
        }
        if (t < L_-2) {  // head 3
            double l0 = a4 + (double)b3[0], l1 = a5 + (double)b3[1];
            double m = fmax(l0, l1);
            double sa = l0 - m, sb = l1 - m;
            double lse = log(exp(sa) + exp(sb));
            float p0l = (float)(sa - lse), p1l = (float)(sb - lse);
            lp[4*L_ + t] = p0l; lp[5*L_ + t] = p1l;
            float p0 = expf(p0l), p1 = expf(p1l);
            e3v = -(p0*p0l + p1*p1l) / LN2F;
        }
        entbuf[t] = e1v; entbuf[L_ + t] = e2v; entbuf[2*L_ + t] = e3v;
    }
}

// ---------------- pre-conflict bools, packed via ballot; nll1 ----------------
__global__ __launch_bounds__(256)
void k_pre(const float* __restrict__ lp,
           const int* __restrict__ al1, const int* __restrict__ al2, const int* __restrict__ al3,
           const float2* __restrict__ g1, const float2* __restrict__ g2, const float2* __restrict__ g3,
           uint64_t* __restrict__ p1w, uint64_t* __restrict__ p2w, uint64_t* __restrict__ p3w,
           float* __restrict__ nll) {
    const int s = blockIdx.y;
    const int t = blockIdx.x * 256 + threadIdx.x;
    const int lane = threadIdx.x & 63;

    float2 v1 = g1[(size_t)s * L_ + t];
    float lp0 = lp[t], lp1v = lp[L_ + t];
    bool raw1 = (lp0 + v1.x) >= (lp1v + v1.y);       // argmax ties -> idx 0
    bool m1 = raw1 && (al1[t] != 0);
    float contrib = raw1 ? -lp0 : -lp1v;             // nll1 uses pre-align argmax

    bool m2 = false, m3 = false;
    if (t < L_-1) {
        float2 v2 = g2[(size_t)s * (L_-1) + t];
        m2 = ((lp[2*L_+t] + v2.x) >= (lp[3*L_+t] + v2.y)) && (al2[t] != 0);
    }
    if (t < L_-2) {
        float2 v3 = g3[(size_t)s * (L_-2) + t];
        m3 = ((lp[4*L_+t] + v3.x) >= (lp[5*L_+t] + v3.y)) && (al3[t] != 0);
    }
    unsigned long long w1b = __ballot(m1);
    unsigned long long w2b = __ballot(m2);
    unsigned long long w3b = __ballot(m3);
    if (lane == 0) {
        int w = t >> 6;            // word-major layout [word][sample]
        p1w[(size_t)w * S_ + s] = w1b;
        p2w[(size_t)w * S_ + s] = w2b;
        p3w[(size_t)w * S_ + s] = w3b;
    }
    #pragma unroll
    for (int o = 32; o > 0; o >>= 1) contrib += __shfl_xor(contrib, o, 64);
    if (lane == 0) atomicAdd(&nll[s], contrib);
}

// ---------------- word-parallel conflict scans ----------------
// pass1: out[t] = c[t] & ~out[t-1]
__device__ __forceinline__ uint64_t pass1_word(uint64_t w, unsigned& carry) {
    uint64_t wp = w & ~(uint64_t)carry;
    uint64_t o = wp & ~(wp << 1);
    uint64_t h = wp & (wp << 1);
    o |= (o << 2)  & h; h &= (h << 2);
    o |= (o << 4)  & h; h &= (h << 4);
    o |= (o << 8)  & h; h &= (h << 8);
    o |= (o << 16) & h; h &= (h << 16);
    o |= (o << 32) & h;
    carry = (unsigned)(o >> 63);
    return o;
}
// pass2: out[t] = a[t] & ~out[t-2]
__device__ __forceinline__ uint64_t pass2_word(uint64_t a, unsigned& qe, unsigned& qo) {
    uint64_t ap = a & ~(uint64_t)qe & ~(((uint64_t)qo) << 1);
    uint64_t o = ap & ~(ap << 2);
    uint64_t h = ap & (ap << 2);
    o |= (o << 4)  & h; h &= (h << 4);
    o |= (o << 8)  & h; h &= (h << 8);
    o |= (o << 16) & h; h &= (h << 16);
    o |= (o << 32) & h;
    qe = (unsigned)((o >> 62) & 1);
    qo = (unsigned)(o >> 63);
    return o;
}

__global__ void k_scan(const uint64_t* __restrict__ p1w, const uint64_t* __restrict__ p2w,
                       const uint64_t* __restrict__ p3w,
                       uint64_t* __restrict__ o1w, uint64_t* __restrict__ o2w,
                       uint64_t* __restrict__ o3w) {
    const int s = blockIdx.x * 64 + threadIdx.x;  // one lane per sample
    unsigned c1 = 0, qe = 0, qo = 0, c2 = 0;
    uint64_t b3m1 = 0, b2m1 = 0;
    uint64_t b3cur = pass2_word(pass1_word(p3w[s], c1), qe, qo);
    for (int j = 0; j < NW; j++) {
        uint64_t b3nx = 0;
        if (j < NW - 1) b3nx = pass2_word(pass1_word(p3w[(size_t)(j+1)*S_ + s], c1), qe, qo);
        uint64_t sh1 = (b3cur << 1) | (b3m1 >> 63);
        uint64_t sh2 = (b3cur << 2) | (b3m1 >> 62);
        uint64_t shm = (b3cur >> 1) | (b3nx << 63);
        uint64_t hit2 = b3cur | sh1 | sh2 | shm;
        uint64_t B2 = pass1_word(p2w[(size_t)j*S_ + s] & ~hit2, c2);
        uint64_t hit1 = b3cur | sh1 | sh2 | B2 | ((B2 << 1) | (b2m1 >> 63));
        uint64_t B1 = p1w[(size_t)j*S_ + s] & ~hit1;
        o3w[(size_t)j*S_ + s] = b3cur;
        o2w[(size_t)j*S_ + s] = B2;
        o1w[(size_t)j*S_ + s] = B1;
        b2m1 = B2; b3m1 = b3cur; b3cur = b3nx;
    }
}

// ---------------- unpack to floats + nll2/nll3 ----------------
__global__ __launch_bounds__(256)
void k_unpack(const uint64_t* __restrict__ o1w, const uint64_t* __restrict__ o2w,
              const uint64_t* __restrict__ o3w, const float* __restrict__ lp,
              float* __restrict__ out) {
    const int s = blockIdx.y;
    const int t = blockIdx.x * 256 + threadIdx.x;
    const int lane = threadIdx.x & 63;
    const int w = t >> 6, b = t & 63;
    float* b1o = out + 2*S_;
    float* b2o = b1o + (size_t)S_ * L_;
    float* b3o = b2o + (size_t)S_ * (L_-1);
    float contrib = 0.0f;
    b1o[(size_t)s*L_ + t] = (float)((o1w[(size_t)w*S_ + s] >> b) & 1);
    if (t < L_-1) {
        unsigned bit = (unsigned)((o2w[(size_t)w*S_ + s] >> b) & 1);
        b2o[(size_t)s*(L_-1) + t] = (float)bit;
        contrib += bit ? -lp[2*L_+t] : -lp[3*L_+t];
    }
    if (t < L_-2) {
        unsigned bit = (unsigned)((o3w[(size_t)w*S_ + s] >> b) & 1);
        b3o[(size_t)s*(L_-2) + t] = (float)bit;
        contrib += bit ? -lp[4*L_+t] : -lp[5*L_+t];
    }
    #pragma unroll
    for (int o = 32; o > 0; o >>= 1) contrib += __shfl_xor(contrib, o, 64);
    if (lane == 0) atomicAdd(&out[S_ + s], contrib);
}

// ---------------- reduce entropy + broadcast nent ----------------
__global__ __launch_bounds__(256)
void k_nent(const float* __restrict__ entbuf, float* __restrict__ out) {
    const int tid = threadIdx.x;
    double s1 = 0, s2 = 0, s3 = 0;
    for (int t = tid; t < L_; t += 256) {
        s1 += (double)entbuf[t];
        s2 += (double)entbuf[L_ + t];    // zeros at invalid tail
        s3 += (double)entbuf[2*L_ + t];
    }
    #pragma unroll
    for (int o = 32; o > 0; o >>= 1) {
        s1 += __shfl_xor(s1, o, 64);
        s2 += __shfl_xor(s2, o, 64);
        s3 += __shfl_xor(s3, o, 64);
    }
    __shared__ double red[3][4];
    const int wid = tid >> 6, lane = tid & 63;
    if (lane == 0) { red[0][wid] = s1; red[1][wid] = s2; red[2][wid] = s3; }
    __syncthreads();
    __shared__ float vsh;
    if (tid == 0) {
        double t1 = red[0][0]+red[0][1]+red[0][2]+red[0][3];
        double t2 = red[1][0]+red[1][1]+red[1][2]+red[1][3];
        double t3 = red[2][0]+red[2][1]+red[2][2]+red[2][3];
        vsh = (float)((t1 / (double)L_ + t2 / (double)(L_-1) + t3 / (double)(L_-2)) / 3.0);
    }
    __syncthreads();
    out[tid] = vsh;
}

extern "C" void kernel_launch(void* const* d_in, const int* in_sizes, int n_in,
                              void* d_out, int out_size, void* d_ws, size_t ws_size,
                              hipStream_t stream) {
    const int*   x    = (const int*)d_in[0];
    // d_in[1] = sample_num (=256), unused
    const int*   al1  = (const int*)d_in[2];
    const int*   al2  = (const int*)d_in[3];
    const int*   al3  = (const int*)d_in[4];
    const float* embd = (const float*)d_in[5];
    const float* w1   = (const float*)d_in[6];
    const float* b1   = (const float*)d_in[7];
    const float* w2   = (const float*)d_in[8];
    const float* b2   = (const float*)d_in[9];
    const float* w3   = (const float*)d_in[10];
    const float* b3   = (const float*)d_in[11];
    const float2* g1  = (const float2*)d_in[12];
    const float2* g2  = (const float2*)d_in[13];
    const float2* g3  = (const float2*)d_in[14];
    float* out = (float*)d_out;

    // ws layout: lp[6][4096] f | entbuf[3][4096] f | 6 x u64[64][256]
    float* lp     = (float*)d_ws;
    float* entbuf = lp + 6 * L_;
    uint8_t* wsb = (uint8_t*)d_ws;
    uint64_t* p1w = (uint64_t*)(wsb + 9 * L_ * 4);
    uint64_t* p2w = p1w + (size_t)NW * S_;
    uint64_t* p3w = p2w + (size_t)NW * S_;
    uint64_t* o1w = p3w + (size_t)NW * S_;
    uint64_t* o2w = o1w + (size_t)NW * S_;
    uint64_t* o3w = o2w + (size_t)NW * S_;

    hipLaunchKernelGGL(k_init, dim3(1), dim3(256), 0, stream, out);
    hipLaunchKernelGGL(k_rows, dim3(1024), dim3(256), 0, stream,
                       x, embd, w1, b1, w2, b2, w3, b3, lp, entbuf);
    hipLaunchKernelGGL(k_pre, dim3(16, S_), dim3(256), 0, stream,
                       lp, al1, al2, al3, g1, g2, g3, p1w, p2w, p3w, out + S_);
    hipLaunchKernelGGL(k_scan, dim3(4), dim3(64), 0, stream,
                       p1w, p2w, p3w, o1w, o2w, o3w);
    hipLaunchKernelGGL(k_unpack, dim3(16, S_), dim3(256), 0, stream,
                       o1w, o2w, o3w, lp, out);
    hipLaunchKernelGGL(k_nent, dim3(1), dim3(256), 0, stream, entbuf, out);
}

// Round 3
// 173.242 us; speedup vs baseline: 2.0551x; 1.5705x over previous
//
#include <hip/hip_runtime.h>
#include <stdint.h>

#define L_ 4096
#define S_ 256
#define D_ 512
#define NW 64  // 64-bit words per length-4096 row

static __device__ const float LN2F = 0.69314718055994530942f;

// ---------------- per-position logits -> logp (one wave per position) ----------------
__global__ __launch_bounds__(256)
void k_rows(const int* __restrict__ x, const float* __restrict__ embd,
            const float* __restrict__ w1, const float* __restrict__ b1,
            const float* __restrict__ w2, const float* __restrict__ b2,
            const float* __restrict__ w3, const float* __restrict__ b3,
            float* __restrict__ lp, float* __restrict__ entbuf) {
    const int wid  = threadIdx.x >> 6;
    const int lane = threadIdx.x & 63;
    const int t = blockIdx.x * 4 + wid;           // grid 1024 -> t in [0,4096)
    const int t1 = (t + 1 < L_) ? t + 1 : t;
    const int t2 = (t + 2 < L_) ? t + 2 : t;
    const int d0 = lane * 8;

    const float4* e0p = (const float4*)(embd + (size_t)x[t]  * D_ + d0);
    const float4* e1p = (const float4*)(embd + (size_t)x[t1] * D_ + d0);
    const float4* e2p = (const float4*)(embd + (size_t)x[t2] * D_ + d0);
    float4 e0a = e0p[0], e0b = e0p[1];
    float4 e1a = e1p[0], e1b = e1p[1];
    float4 e2a = e2p[0], e2b = e2p[1];
    const float4* w1p = (const float4*)(w1 + 2 * d0);
    const float4* w2p = (const float4*)(w2 + 2 * d0);
    const float4* w3p = (const float4*)(w3 + 2 * d0);

    float v0[8] = {e0a.x,e0a.y,e0a.z,e0a.w,e0b.x,e0b.y,e0b.z,e0b.w};
    float v1[8] = {e1a.x,e1a.y,e1a.z,e1a.w,e1b.x,e1b.y,e1b.z,e1b.w};
    float v2[8] = {e2a.x,e2a.y,e2a.z,e2a.w,e2b.x,e2b.y,e2b.z,e2b.w};
    float wv1[16], wv2[16], wv3[16];
    for (int q = 0; q < 4; q++) {
        float4 a = w1p[q]; wv1[4*q]=a.x; wv1[4*q+1]=a.y; wv1[4*q+2]=a.z; wv1[4*q+3]=a.w;
        float4 b = w2p[q]; wv2[4*q]=b.x; wv2[4*q+1]=b.y; wv2[4*q+2]=b.z; wv2[4*q+3]=b.w;
        float4 c = w3p[q]; wv3[4*q]=c.x; wv3[4*q+1]=c.y; wv3[4*q+2]=c.z; wv3[4*q+3]=c.w;
    }
    double a0=0,a1=0,a2=0,a3=0,a4=0,a5=0;
    #pragma unroll
    for (int j = 0; j < 8; j++) {
        float s2 = (v1[j] + v0[j]) * 0.5f;        // reference order in f32
        float s3 = ((v2[j] + v1[j]) + v0[j]) / 3.0f;
        a0 += (double)v0[j] * (double)wv1[2*j];
        a1 += (double)v0[j] * (double)wv1[2*j+1];
        a2 += (double)s2    * (double)wv2[2*j];
        a3 += (double)s2    * (double)wv2[2*j+1];
        a4 += (double)s3    * (double)wv3[2*j];
        a5 += (double)s3    * (double)wv3[2*j+1];
    }
    #pragma unroll
    for (int o = 32; o > 0; o >>= 1) {
        a0 += __shfl_xor(a0, o, 64);
        a1 += __shfl_xor(a1, o, 64);
        a2 += __shfl_xor(a2, o, 64);
        a3 += __shfl_xor(a3, o, 64);
        a4 += __shfl_xor(a4, o, 64);
        a5 += __shfl_xor(a5, o, 64);
    }
    // lanes 0/1/2 each handle one head in parallel (all lanes hold all sums)
    if (lane < 3) {
        double l0, l1; const float* bb;
        if (lane == 0)      { l0 = a0; l1 = a1; bb = b1; }
        else if (lane == 1) { l0 = a2; l1 = a3; bb = b2; }
        else                { l0 = a4; l1 = a5; bb = b3; }
        bool valid = (lane == 0) || (lane == 1 && t < L_-1) || (lane == 2 && t < L_-2);
        float ev = 0.0f;
        if (valid) {
            l0 += (double)bb[0]; l1 += (double)bb[1];
            double m = fmax(l0, l1);
            double sa = l0 - m, sb = l1 - m;
            double lse = log(exp(sa) + exp(sb));
            float p0l = (float)(sa - lse), p1l = (float)(sb - lse);
            lp[2*lane*L_ + t] = p0l; lp[(2*lane+1)*L_ + t] = p1l;
            float p0 = expf(p0l), p1 = expf(p1l);
            ev = -(p0*p0l + p1*p1l) / LN2F;
        }
        entbuf[lane*L_ + t] = ev;
    }
}

// ---------------- word-parallel conflict scan primitives ----------------
// pass1: out[t] = c[t] & ~out[t-1]
__device__ __forceinline__ uint64_t pass1_word(uint64_t w, unsigned& carry) {
    uint64_t wp = w & ~(uint64_t)carry;
    uint64_t o = wp & ~(wp << 1);
    uint64_t h = wp & (wp << 1);
    o |= (o << 2)  & h; h &= (h << 2);
    o |= (o << 4)  & h; h &= (h << 4);
    o |= (o << 8)  & h; h &= (h << 8);
    o |= (o << 16) & h; h &= (h << 16);
    o |= (o << 32) & h;
    carry = (unsigned)(o >> 63);
    return o;
}
// pass2: out[t] = a[t] & ~out[t-2]
__device__ __forceinline__ uint64_t pass2_word(uint64_t a, unsigned& qe, unsigned& qo) {
    uint64_t ap = a & ~(uint64_t)qe & ~(((uint64_t)qo) << 1);
    uint64_t o = ap & ~(ap << 2);
    uint64_t h = ap & (ap << 2);
    o |= (o << 4)  & h; h &= (h << 4);
    o |= (o << 8)  & h; h &= (h << 8);
    o |= (o << 16) & h; h &= (h << 16);
    o |= (o << 32) & h;
    qe = (unsigned)((o >> 62) & 1);
    qo = (unsigned)(o >> 63);
    return o;
}

// ---------------- fused: masks -> LDS scan -> unpack + nll ----------------
__global__ __launch_bounds__(1024)
void k_fused(const float* __restrict__ lp,
             const int* __restrict__ al1, const int* __restrict__ al2, const int* __restrict__ al3,
             const float2* __restrict__ g1, const float2* __restrict__ g2, const float2* __restrict__ g3,
             float* __restrict__ out) {
    const int s = blockIdx.x;
    const int tid = threadIdx.x;
    const int lane = tid & 63;
    const int wv = tid >> 6;           // 0..15

    __shared__ uint64_t w1s[NW], w2s[NW], w3s[NW];
    __shared__ uint64_t o1s[NW], o2s[NW], o3s[NW];

    float lp2a[4], lp2b[4], lp3a[4], lp3b[4];
    float nllacc = 0.0f;
    #pragma unroll
    for (int it = 0; it < 4; it++) {
        const int t = it * 1024 + tid;
        float2 v1 = g1[(size_t)s * L_ + t];
        float lp0 = lp[t], lp1v = lp[L_ + t];
        bool raw1 = (lp0 + v1.x) >= (lp1v + v1.y);   // argmax ties -> idx 0
        bool m1 = raw1 && (al1[t] != 0);
        nllacc += raw1 ? -lp0 : -lp1v;               // nll1: pre-align argmax
        bool m2 = false, m3 = false;
        lp2a[it] = 0.f; lp2b[it] = 0.f; lp3a[it] = 0.f; lp3b[it] = 0.f;
        if (t < L_-1) {
            float2 v2 = g2[(size_t)s * (L_-1) + t];
            float a = lp[2*L_+t], b = lp[3*L_+t];
            lp2a[it] = a; lp2b[it] = b;
            m2 = ((a + v2.x) >= (b + v2.y)) && (al2[t] != 0);
        }
        if (t < L_-2) {
            float2 v3 = g3[(size_t)s * (L_-2) + t];
            float a = lp[4*L_+t], b = lp[5*L_+t];
            lp3a[it] = a; lp3b[it] = b;
            m3 = ((a + v3.x) >= (b + v3.y)) && (al3[t] != 0);
        }
        unsigned long long b1b = __ballot(m1);
        unsigned long long b2b = __ballot(m2);
        unsigned long long b3b = __ballot(m3);
        if (lane == 0) {
            int w = t >> 6;
            w1s[w] = b1b; w2s[w] = b2b; w3s[w] = b3b;
        }
    }
    __syncthreads();

    if (tid == 0) {   // serial conflict scan, all in LDS (~64 iters)
        unsigned c1 = 0, qe = 0, qo = 0, c2 = 0;
        uint64_t b3m1 = 0, b2m1 = 0;
        uint64_t b3cur = pass2_word(pass1_word(w3s[0], c1), qe, qo);
        for (int j = 0; j < NW; j++) {
            uint64_t b3nx = 0;
            if (j < NW - 1) b3nx = pass2_word(pass1_word(w3s[j+1], c1), qe, qo);
            uint64_t sh1 = (b3cur << 1) | (b3m1 >> 63);
            uint64_t sh2 = (b3cur << 2) | (b3m1 >> 62);
            uint64_t shm = (b3cur >> 1) | (b3nx << 63);
            uint64_t hit2 = b3cur | sh1 | sh2 | shm;
            uint64_t B2 = pass1_word(w2s[j] & ~hit2, c2);
            uint64_t hit1 = b3cur | sh1 | sh2 | B2 | ((B2 << 1) | (b2m1 >> 63));
            uint64_t B1 = w1s[j] & ~hit1;
            o3s[j] = b3cur; o2s[j] = B2; o1s[j] = B1;
            b2m1 = B2; b3m1 = b3cur; b3cur = b3nx;
        }
    }
    __syncthreads();

    float* b1o = out + 2*S_;
    float* b2o = b1o + (size_t)S_ * L_;
    float* b3o = b2o + (size_t)S_ * (L_-1);
    #pragma unroll
    for (int it = 0; it < 4; it++) {
        const int t = it * 1024 + tid;
        const int w = t >> 6, b = t & 63;
        b1o[(size_t)s*L_ + t] = (float)((o1s[w] >> b) & 1);
        if (t < L_-1) {
            unsigned bit = (unsigned)((o2s[w] >> b) & 1);
            b2o[(size_t)s*(L_-1) + t] = (float)bit;
            nllacc += bit ? -lp2a[it] : -lp2b[it];
        }
        if (t < L_-2) {
            unsigned bit = (unsigned)((o3s[w] >> b) & 1);
            b3o[(size_t)s*(L_-2) + t] = (float)bit;
            nllacc += bit ? -lp3a[it] : -lp3b[it];
        }
    }
    #pragma unroll
    for (int o = 32; o > 0; o >>= 1) nllacc += __shfl_xor(nllacc, o, 64);
    __shared__ float red[16];
    if (lane == 0) red[wv] = nllacc;
    __syncthreads();
    if (tid == 0) {
        float tot = 0.f;
        #pragma unroll
        for (int i = 0; i < 16; i++) tot += red[i];
        out[S_ + s] = tot;   // direct store — no atomics, no init kernel
    }
}

// ---------------- reduce entropy + broadcast nent ----------------
__global__ __launch_bounds__(256)
void k_nent(const float* __restrict__ entbuf, float* __restrict__ out) {
    const int tid = threadIdx.x;
    double s1 = 0, s2 = 0, s3 = 0;
    for (int t = tid; t < L_; t += 256) {
        s1 += (double)entbuf[t];
        s2 += (double)entbuf[L_ + t];
        s3 += (double)entbuf[2*L_ + t];
    }
    #pragma unroll
    for (int o = 32; o > 0; o >>= 1) {
        s1 += __shfl_xor(s1, o, 64);
        s2 += __shfl_xor(s2, o, 64);
        s3 += __shfl_xor(s3, o, 64);
    }
    __shared__ double red[3][4];
    const int wid = tid >> 6, lane = tid & 63;
    if (lane == 0) { red[0][wid] = s1; red[1][wid] = s2; red[2][wid] = s3; }
    __syncthreads();
    __shared__ float vsh;
    if (tid == 0) {
        double t1 = red[0][0]+red[0][1]+red[0][2]+red[0][3];
        double t2 = red[1][0]+red[1][1]+red[1][2]+red[1][3];
        double t3 = red[2][0]+red[2][1]+red[2][2]+red[2][3];
        vsh = (float)((t1 / (double)L_ + t2 / (double)(L_-1) + t3 / (double)(L_-2)) / 3.0);
    }
    __syncthreads();
    out[tid] = vsh;
}

extern "C" void kernel_launch(void* const* d_in, const int* in_sizes, int n_in,
                              void* d_out, int out_size, void* d_ws, size_t ws_size,
                              hipStream_t stream) {
    const int*   x    = (const int*)d_in[0];
    const int*   al1  = (const int*)d_in[2];
    const int*   al2  = (const int*)d_in[3];
    const int*   al3  = (const int*)d_in[4];
    const float* embd = (const float*)d_in[5];
    const float* w1   = (const float*)d_in[6];
    const float* b1   = (const float*)d_in[7];
    const float* w2   = (const float*)d_in[8];
    const float* b2   = (const float*)d_in[9];
    const float* w3   = (const float*)d_in[10];
    const float* b3   = (const float*)d_in[11];
    const float2* g1  = (const float2*)d_in[12];
    const float2* g2  = (const float2*)d_in[13];
    const float2* g3  = (const float2*)d_in[14];
    float* out = (float*)d_out;

    // ws layout: lp[6][4096] f | entbuf[3][4096] f
    float* lp     = (float*)d_ws;
    float* entbuf = lp + 6 * L_;

    hipLaunchKernelGGL(k_rows, dim3(1024), dim3(256), 0, stream,
                       x, embd, w1, b1, w2, b2, w3, b3, lp, entbuf);
    hipLaunchKernelGGL(k_fused, dim3(S_), dim3(1024), 0, stream,
                       lp, al1, al2, al3, g1, g2, g3, out);
    hipLaunchKernelGGL(k_nent, dim3(1), dim3(256), 0, stream, entbuf, out);
}

// Round 4
// 168.450 us; speedup vs baseline: 2.1135x; 1.0284x over previous
//
#include <hip/hip_runtime.h>
#include <stdint.h>

#define L_ 4096
#define S_ 256
#define D_ 512
#define NW 64  // 64-bit words per length-4096 row

static __device__ const float LN2F = 0.69314718055994530942f;

// ---------------- per-position logits -> logp (one wave per position) ----------------
__global__ __launch_bounds__(256)
void k_rows(const int* __restrict__ x, const float* __restrict__ embd,
            const float* __restrict__ w1, const float* __restrict__ b1,
            const float* __restrict__ w2, const float* __restrict__ b2,
            const float* __restrict__ w3, const float* __restrict__ b3,
            float* __restrict__ lp, float* __restrict__ entbuf) {
    const int wid  = threadIdx.x >> 6;
    const int lane = threadIdx.x & 63;
    const int t = blockIdx.x * 4 + wid;           // grid 1024 -> t in [0,4096)
    const int t1 = (t + 1 < L_) ? t + 1 : t;
    const int t2 = (t + 2 < L_) ? t + 2 : t;
    const int d0 = lane * 8;

    const float4* e0p = (const float4*)(embd + (size_t)x[t]  * D_ + d0);
    const float4* e1p = (const float4*)(embd + (size_t)x[t1] * D_ + d0);
    const float4* e2p = (const float4*)(embd + (size_t)x[t2] * D_ + d0);
    float4 e0a = e0p[0], e0b = e0p[1];
    float4 e1a = e1p[0], e1b = e1p[1];
    float4 e2a = e2p[0], e2b = e2p[1];
    const float4* w1p = (const float4*)(w1 + 2 * d0);
    const float4* w2p = (const float4*)(w2 + 2 * d0);
    const float4* w3p = (const float4*)(w3 + 2 * d0);

    float v0[8] = {e0a.x,e0a.y,e0a.z,e0a.w,e0b.x,e0b.y,e0b.z,e0b.w};
    float v1[8] = {e1a.x,e1a.y,e1a.z,e1a.w,e1b.x,e1b.y,e1b.z,e1b.w};
    float v2[8] = {e2a.x,e2a.y,e2a.z,e2a.w,e2b.x,e2b.y,e2b.z,e2b.w};
    float wv1[16], wv2[16], wv3[16];
    for (int q = 0; q < 4; q++) {
        float4 a = w1p[q]; wv1[4*q]=a.x; wv1[4*q+1]=a.y; wv1[4*q+2]=a.z; wv1[4*q+3]=a.w;
        float4 b = w2p[q]; wv2[4*q]=b.x; wv2[4*q+1]=b.y; wv2[4*q+2]=b.z; wv2[4*q+3]=b.w;
        float4 c = w3p[q]; wv3[4*q]=c.x; wv3[4*q+1]=c.y; wv3[4*q+2]=c.z; wv3[4*q+3]=c.w;
    }
    double a0=0,a1=0,a2=0,a3=0,a4=0,a5=0;
    #pragma unroll
    for (int j = 0; j < 8; j++) {
        float s2 = (v1[j] + v0[j]) * 0.5f;        // reference order in f32
        float s3 = ((v2[j] + v1[j]) + v0[j]) / 3.0f;
        a0 += (double)v0[j] * (double)wv1[2*j];
        a1 += (double)v0[j] * (double)wv1[2*j+1];
        a2 += (double)s2    * (double)wv2[2*j];
        a3 += (double)s2    * (double)wv2[2*j+1];
        a4 += (double)s3    * (double)wv3[2*j];
        a5 += (double)s3    * (double)wv3[2*j+1];
    }
    #pragma unroll
    for (int o = 32; o > 0; o >>= 1) {
        a0 += __shfl_xor(a0, o, 64);
        a1 += __shfl_xor(a1, o, 64);
        a2 += __shfl_xor(a2, o, 64);
        a3 += __shfl_xor(a3, o, 64);
        a4 += __shfl_xor(a4, o, 64);
        a5 += __shfl_xor(a5, o, 64);
    }
    // lanes 0/1/2 each handle one head in parallel (all lanes hold all sums)
    if (lane < 3) {
        double l0, l1; const float* bb;
        if (lane == 0)      { l0 = a0; l1 = a1; bb = b1; }
        else if (lane == 1) { l0 = a2; l1 = a3; bb = b2; }
        else                { l0 = a4; l1 = a5; bb = b3; }
        bool valid = (lane == 0) || (lane == 1 && t < L_-1) || (lane == 2 && t < L_-2);
        float ev = 0.0f;
        if (valid) {
            l0 += (double)bb[0]; l1 += (double)bb[1];
            double m = fmax(l0, l1);
            double sa = l0 - m, sb = l1 - m;
            double lse = log(exp(sa) + exp(sb));
            float p0l = (float)(sa - lse), p1l = (float)(sb - lse);
            lp[2*lane*L_ + t] = p0l; lp[(2*lane+1)*L_ + t] = p1l;
            float p0 = expf(p0l), p1 = expf(p1l);
            ev = -(p0*p0l + p1*p1l) / LN2F;
        }
        entbuf[lane*L_ + t] = ev;
    }
}

// ---------------- word-local conflict primitives (no carry-in; caller masks) ----------------
// out[t] = c[t] & ~out[t-1] within a word, assuming out[-1]=0
__device__ __forceinline__ uint64_t pass1_noc(uint64_t wp) {
    uint64_t o = wp & ~(wp << 1);
    uint64_t h = wp & (wp << 1);
    o |= (o << 2)  & h; h &= (h << 2);
    o |= (o << 4)  & h; h &= (h << 4);
    o |= (o << 8)  & h; h &= (h << 8);
    o |= (o << 16) & h; h &= (h << 16);
    o |= (o << 32) & h;
    return o;
}
// out[t] = a[t] & ~out[t-2] within a word, assuming out[-1]=out[-2]=0
__device__ __forceinline__ uint64_t pass2_noc(uint64_t ap) {
    uint64_t o = ap & ~(ap << 2);
    uint64_t h = ap & (ap << 2);
    o |= (o << 4)  & h; h &= (h << 4);
    o |= (o << 8)  & h; h &= (h << 8);
    o |= (o << 16) & h; h &= (h << 16);
    o |= (o << 32) & h;
    return o;
}

// ---------------- fused: masks -> parallel LDS scan -> unpack + nll (+nent in blk0) ----------------
__global__ __launch_bounds__(1024)
void k_fused(const float* __restrict__ lp,
             const int* __restrict__ al1, const int* __restrict__ al2, const int* __restrict__ al3,
             const float2* __restrict__ g1, const float2* __restrict__ g2, const float2* __restrict__ g3,
             const float* __restrict__ entbuf, float* __restrict__ out) {
    const int s = blockIdx.x;
    const int tid = threadIdx.x;
    const int lane = tid & 63;
    const int wv = tid >> 6;           // 0..15

    __shared__ uint64_t w1s[NW], w2s[NW], w3s[NW];
    __shared__ uint64_t o1s[NW], o2s[NW], o3s[NW];

    float lp2a[4], lp2b[4], lp3a[4], lp3b[4];
    float nllacc = 0.0f;
    #pragma unroll
    for (int it = 0; it < 4; it++) {
        const int t = it * 1024 + tid;
        float2 v1 = g1[(size_t)s * L_ + t];
        float lp0 = lp[t], lp1v = lp[L_ + t];
        bool raw1 = (lp0 + v1.x) >= (lp1v + v1.y);   // argmax ties -> idx 0
        bool m1 = raw1 && (al1[t] != 0);
        nllacc += raw1 ? -lp0 : -lp1v;               // nll1: pre-align argmax
        bool m2 = false, m3 = false;
        lp2a[it] = 0.f; lp2b[it] = 0.f; lp3a[it] = 0.f; lp3b[it] = 0.f;
        if (t < L_-1) {
            float2 v2 = g2[(size_t)s * (L_-1) + t];
            float a = lp[2*L_+t], b = lp[3*L_+t];
            lp2a[it] = a; lp2b[it] = b;
            m2 = ((a + v2.x) >= (b + v2.y)) && (al2[t] != 0);
        }
        if (t < L_-2) {
            float2 v3 = g3[(size_t)s * (L_-2) + t];
            float a = lp[4*L_+t], b = lp[5*L_+t];
            lp3a[it] = a; lp3b[it] = b;
            m3 = ((a + v3.x) >= (b + v3.y)) && (al3[t] != 0);
        }
        unsigned long long b1b = __ballot(m1);
        unsigned long long b2b = __ballot(m2);
        unsigned long long b3b = __ballot(m3);
        if (lane == 0) {
            int w = t >> 6;
            w1s[w] = b1b; w2s[w] = b2b; w3s[w] = b3b;
        }
    }
    __syncthreads();

    // ---- parallel conflict scan: wave 0, lane j owns word j ----
    if (wv == 0) {
        const int j = lane;
        // b3 pass1: evaluate for carry-in 0 and 1; compose 1-bit transfer funcs
        uint64_t w3 = w3s[j];
        uint64_t oA = pass1_noc(w3);
        uint64_t oB = pass1_noc(w3 & ~1ull);
        unsigned F = (unsigned)(oA >> 63) | (((unsigned)(oB >> 63)) << 1);  // (f(0), f(1))
        #pragma unroll
        for (int d = 1; d < 64; d <<= 1) {
            unsigned P = __shfl_up(F, d, 64);
            if (lane >= d) {    // compose: new(x) = F[P[x]]
                unsigned la = P & 1, lb = (P >> 1) & 1;
                unsigned ra = F & 1, rb = (F >> 1) & 1;
                F = (la ? rb : ra) | ((lb ? rb : ra) << 1);
            }
        }
        unsigned Fp = __shfl_up(F, 1, 64);
        unsigned cin = (lane == 0) ? 0u : (Fp & 1);
        uint64_t p1 = cin ? oB : oA;

        // b3 pass2: 4 carry states (qe=bit0 masks out bit0, qo=bit1 masks bit1)
        uint64_t q0 = pass2_noc(p1);
        uint64_t q1 = pass2_noc(p1 & ~1ull);
        uint64_t q2 = pass2_noc(p1 & ~2ull);
        uint64_t q3 = pass2_noc(p1 & ~3ull);
        #define ST_(o) ((unsigned)(((o >> 62) & 1) | (((o >> 63) & 1) << 1)))
        unsigned G = ST_(q0) | (ST_(q1) << 2) | (ST_(q2) << 4) | (ST_(q3) << 6);
        #undef ST_
        #pragma unroll
        for (int d = 1; d < 64; d <<= 1) {
            unsigned P = __shfl_up(G, d, 64);
            if (lane >= d) {    // compose: H[x] = G[P[x]]
                unsigned H = 0;
                #pragma unroll
                for (int xx = 0; xx < 4; xx++) {
                    unsigned m = (P >> (2 * xx)) & 3;
                    H |= ((G >> (2 * m)) & 3) << (2 * xx);
                }
                G = H;
            }
        }
        unsigned Gp = __shfl_up(G, 1, 64);
        unsigned s2in = (lane == 0) ? 0u : (Gp & 3);
        uint64_t B3 = (s2in == 0) ? q0 : (s2in == 1) ? q1 : (s2in == 2) ? q2 : q3;

        // neighbors of B3
        uint64_t B3m1 = __shfl_up((unsigned long long)B3, 1, 64); if (lane == 0)  B3m1 = 0;
        uint64_t B3nx = __shfl_down((unsigned long long)B3, 1, 64); if (lane == 63) B3nx = 0;
        uint64_t sh1 = (B3 << 1) | (B3m1 >> 63);
        uint64_t sh2 = (B3 << 2) | (B3m1 >> 62);
        uint64_t shm = (B3 >> 1) | (B3nx << 63);
        uint64_t hit2 = B3 | sh1 | sh2 | shm;

        // b2 pass1 with its own 1-bit carry chain
        uint64_t in2 = w2s[j] & ~hit2;
        uint64_t oA2 = pass1_noc(in2);
        uint64_t oB2 = pass1_noc(in2 & ~1ull);
        unsigned F2 = (unsigned)(oA2 >> 63) | (((unsigned)(oB2 >> 63)) << 1);
        #pragma unroll
        for (int d = 1; d < 64; d <<= 1) {
            unsigned P = __shfl_up(F2, d, 64);
            if (lane >= d) {
                unsigned la = P & 1, lb = (P >> 1) & 1;
                unsigned ra = F2 & 1, rb = (F2 >> 1) & 1;
                F2 = (la ? rb : ra) | ((lb ? rb : ra) << 1);
            }
        }
        unsigned F2p = __shfl_up(F2, 1, 64);
        unsigned cin2 = (lane == 0) ? 0u : (F2p & 1);
        uint64_t B2 = cin2 ? oB2 : oA2;

        uint64_t B2m1 = __shfl_up((unsigned long long)B2, 1, 64); if (lane == 0) B2m1 = 0;
        uint64_t hit1 = B3 | sh1 | sh2 | B2 | ((B2 << 1) | (B2m1 >> 63));
        uint64_t B1 = w1s[j] & ~hit1;

        o1s[j] = B1; o2s[j] = B2; o3s[j] = B3;
    }
    __syncthreads();

    float* b1o = out + 2*S_;
    float* b2o = b1o + (size_t)S_ * L_;
    float* b3o = b2o + (size_t)S_ * (L_-1);
    #pragma unroll
    for (int it = 0; it < 4; it++) {
        const int t = it * 1024 + tid;
        const int w = t >> 6, b = t & 63;
        b1o[(size_t)s*L_ + t] = (float)((o1s[w] >> b) & 1);
        if (t < L_-1) {
            unsigned bit = (unsigned)((o2s[w] >> b) & 1);
            b2o[(size_t)s*(L_-1) + t] = (float)bit;
            nllacc += bit ? -lp2a[it] : -lp2b[it];
        }
        if (t < L_-2) {
            unsigned bit = (unsigned)((o3s[w] >> b) & 1);
            b3o[(size_t)s*(L_-2) + t] = (float)bit;
            nllacc += bit ? -lp3a[it] : -lp3b[it];
        }
    }
    #pragma unroll
    for (int o = 32; o > 0; o >>= 1) nllacc += __shfl_xor(nllacc, o, 64);
    __shared__ float red[16];
    if (lane == 0) red[wv] = nllacc;
    __syncthreads();
    if (tid == 0) {
        float tot = 0.f;
        #pragma unroll
        for (int i = 0; i < 16; i++) tot += red[i];
        out[S_ + s] = tot;
    }

    // ---- nent tail: block 0, wave 0 only (entbuf ready from k_rows) ----
    if (s == 0 && wv == 0) {
        double s1 = 0, s2d = 0, s3d = 0;
        for (int t = lane; t < L_; t += 64) {
            s1  += (double)entbuf[t];
            s2d += (double)entbuf[L_ + t];
            s3d += (double)entbuf[2*L_ + t];
        }
        #pragma unroll
        for (int o = 32; o > 0; o >>= 1) {
            s1  += __shfl_xor(s1, o, 64);
            s2d += __shfl_xor(s2d, o, 64);
            s3d += __shfl_xor(s3d, o, 64);
        }
        float v = (float)((s1 / (double)L_ + s2d / (double)(L_-1) + s3d / (double)(L_-2)) / 3.0);
        #pragma unroll
        for (int i = 0; i < 4; i++) out[lane + 64*i] = v;
    }
}

extern "C" void kernel_launch(void* const* d_in, const int* in_sizes, int n_in,
                              void* d_out, int out_size, void* d_ws, size_t ws_size,
                              hipStream_t stream) {
    const int*   x    = (const int*)d_in[0];
    const int*   al1  = (const int*)d_in[2];
    const int*   al2  = (const int*)d_in[3];
    const int*   al3  = (const int*)d_in[4];
    const float* embd = (const float*)d_in[5];
    const float* w1   = (const float*)d_in[6];
    const float* b1   = (const float*)d_in[7];
    const float* w2   = (const float*)d_in[8];
    const float* b2   = (const float*)d_in[9];
    const float* w3   = (const float*)d_in[10];
    const float* b3   = (const float*)d_in[11];
    const float2* g1  = (const float2*)d_in[12];
    const float2* g2  = (const float2*)d_in[13];
    const float2* g3  = (const float2*)d_in[14];
    float* out = (float*)d_out;

    // ws layout: lp[6][4096] f | entbuf[3][4096] f
    float* lp     = (float*)d_ws;
    float* entbuf = lp + 6 * L_;

    hipLaunchKernelGGL(k_rows, dim3(1024), dim3(256), 0, stream,
                       x, embd, w1, b1, w2, b2, w3, b3, lp, entbuf);
    hipLaunchKernelGGL(k_fused, dim3(S_), dim3(1024), 0, stream,
                       lp, al1, al2, al3, g1, g2, g3, entbuf, out);
}